// Round 6
// baseline (293.301 us; speedup 1.0000x reference)
//
#include <hip/hip_runtime.h>
#include <hip/hip_bf16.h>
#include <math.h>

// Problem: B=2, H=12, S=2048, D=64. Device I/O: f32 inputs, f32 outputs.
#define B_SZ   2
#define NH     12
#define S_LEN  2048
#define D_HD   64
#define NQ_EL  ((size_t)B_SZ * NH * S_LEN * D_HD)   // 3,145,728 per tensor

typedef __attribute__((ext_vector_type(8))) __bf16 bf16x8;
typedef __attribute__((ext_vector_type(4))) __bf16 bf16x4;
typedef __attribute__((ext_vector_type(4))) float  f32x4;

// ---------------- mask layout detection --------------------------------------
// mode: 0=int32{0,1} 1=uint8{0,1} 2=f32{0.0,1.0} 3=bf16{0.0,1.0}
__device__ __forceinline__ int detect_mask_mode64(const void* mask) {
  const int lane = threadIdx.x & 63;
  unsigned v = ((const unsigned*)mask)[lane];
  if (__ballot(v <= 1u) == ~0ull) return 0;
  if (__ballot(v == 0u || v == 0x3f800000u) == ~0ull) return 2;
  unsigned h0 = v & 0xFFFFu, h1 = v >> 16;
  bool okb = (h0 == 0u || h0 == 0x3f80u) && (h1 == 0u || h1 == 0x3f80u);
  if (__ballot(okb) == ~0ull) return 3;
  return 1;
}

__device__ __forceinline__ bool mask_at(const void* mask, int mode, size_t idx) {
  if (mode == 0) return ((const int*)mask)[idx] != 0;
  if (mode == 1) return ((const unsigned char*)mask)[idx] != 0;
  if (mode == 2) return ((const float*)mask)[idx] != 0.0f;
  return ((const unsigned short*)mask)[idx] != 0;
}

// Compress mask [B,1,S,S] -> 1 MB bitmask (XCD-L2-resident for all re-reads).
__global__ __launch_bounds__(256)
void build_bits_kernel(const void* __restrict__ mask, unsigned* __restrict__ bits) {
  const int mode = detect_mask_mode64(mask);
  const size_t i = (size_t)blockIdx.x * 256 + threadIdx.x;
  const bool m = mask_at(mask, mode, i);
  const unsigned long long bal = __ballot(m);
  const int lane = threadIdx.x & 63;
  if (lane == 0)       bits[i >> 5] = (unsigned)bal;
  else if (lane == 32) bits[i >> 5] = (unsigned)(bal >> 32);
}

// Convert Q(*0.125, exact pow2), K, V f32 -> bf16 workspace (RTE).
__global__ __launch_bounds__(256)
void convert_kernel(const float* __restrict__ Q, const float* __restrict__ K,
                    const float* __restrict__ V,
                    __bf16* __restrict__ Qb, __bf16* __restrict__ Kb,
                    __bf16* __restrict__ Vb) {
  const size_t nvec = NQ_EL / 4;
  for (size_t vi = (size_t)blockIdx.x * 256 + threadIdx.x; vi < 3 * nvec;
       vi += (size_t)gridDim.x * 256) {
    const int seg = vi < nvec ? 0 : (vi < 2 * nvec ? 1 : 2);
    const size_t li = vi - (size_t)seg * nvec;
    const float* src = seg == 0 ? Q : (seg == 1 ? K : V);
    __bf16* dst = seg == 0 ? Qb : (seg == 1 ? Kb : Vb);
    const float scale = seg == 0 ? 0.125f : 1.0f;
    float4 a = ((const float4*)src)[li];
    __bf16 o0 = (__bf16)(a.x * scale), o1 = (__bf16)(a.y * scale);
    __bf16 o2 = (__bf16)(a.z * scale), o3 = (__bf16)(a.w * scale);
    ((ushort4*)dst)[li] = (ushort4){
        __builtin_bit_cast(unsigned short, o0), __builtin_bit_cast(unsigned short, o1),
        __builtin_bit_cast(unsigned short, o2), __builtin_bit_cast(unsigned short, o3)};
  }
}

// ---------------- typed load helpers -----------------------------------------
__device__ __forceinline__ bf16x8 ld8s(const __bf16* p, float) {
  return *(const bf16x8*)p;
}
__device__ __forceinline__ bf16x8 ld8s(const float* p, float scale) {
  const float4 a = *(const float4*)p;
  const float4 b = *(const float4*)(p + 4);
  bf16x8 r;
  r[0] = (__bf16)(a.x * scale); r[1] = (__bf16)(a.y * scale);
  r[2] = (__bf16)(a.z * scale); r[3] = (__bf16)(a.w * scale);
  r[4] = (__bf16)(b.x * scale); r[5] = (__bf16)(b.y * scale);
  r[6] = (__bf16)(b.z * scale); r[7] = (__bf16)(b.w * scale);
  return r;
}

// ---------------- fused attention --------------------------------------------
// 768 blocks x 512 thr (8 waves), XCD-contiguous remap (768 = 8 x 96).
// Waves (qw, kh): qw 0..3 owns 16 q-rows, kh 0..1 sweeps one k-half (split-K).
// SWAPPED QK^T: acc = mfma(A=K-frag, B=Q-frag) -> C col=lane&15 = q-index,
// row=(lane>>4)*4+r = key-slot. Lane (col,g) holds P[qbase+col][kb+g*4+r]:
// P is lane-local per q-row => no LDS P round-trip, float4 prob stores,
// softmax reduce = 2 shuffles. PV: A=P in-register with k-order
// sigma(g,e)=(e>>2)*16+g*4+(e&3); B=V-frag read from vt with the SAME sigma
// (two b64 reads at k-offsets g*4 and 16+g*4) -> bijection cancels (the same
// argument HW-verified by rounds 4/5 passing + learn_hip m89/m97).
// vt is double-buffered: stage chunk it+1 while computing it; ONE barrier/iter.
template<typename T, bool USE_BITS, bool PRESCALED>
__global__ __launch_bounds__(512)
void attn_kernel(const T* __restrict__ Qg, const T* __restrict__ Kg,
                 const T* __restrict__ Vg, const void* __restrict__ mask,
                 const unsigned* __restrict__ mbits, float* __restrict__ out_ctx)
{
  float* out_p = out_ctx + NQ_EL;

  const int flat = blockIdx.x + blockIdx.y * gridDim.x;    // 0..767
  const int wf   = (flat & 7) * 96 + (flat >> 3);          // XCD-contiguous
  const int qt   = wf & 31;
  const int bh   = wf >> 5;
  const int b    = bh / NH;

  const int tid  = threadIdx.x;
  const int lane = tid & 63;
  const int w    = tid >> 6;             // 0..7
  const int qw   = w & 3;
  const int kh   = w >> 2;               // k-half
  const int qbase = qt * 64 + qw * 16;
  const int col  = lane & 15;
  const int g    = lane >> 4;
  const int q    = qbase + col;          // this lane's q-row
  const int k0   = kh * (S_LEN / 2);

  int mmode = 0;
  if constexpr (!USE_BITS) mmode = detect_mask_mode64(mask);
  const size_t mrow  = (size_t)b * S_LEN * S_LEN;
  const size_t mbase = ((size_t)b * S_LEN + q) * (S_LEN / 32);

  // Q as B-frag: lane col = q-row, dims g*8..g*8+7 (+32).
  const size_t qoff = ((size_t)bh * S_LEN + q) * D_HD + g * 8;
  const bf16x8 bq0 = ld8s(Qg + qoff,      PRESCALED ? 1.0f : 0.125f);
  const bf16x8 bq1 = ld8s(Qg + qoff + 32, PRESCALED ? 1.0f : 0.125f);

  // ---------------- Pass 1: row sum of exp over own k-half ------------------
  float lsum = 0.f;
#pragma unroll 2
  for (int kc = k0; kc < k0 + S_LEN / 2; kc += 32) {
    unsigned mw = 0;
    if constexpr (USE_BITS) mw = mbits[mbase + (kc >> 5)];
#pragma unroll
    for (int sub = 0; sub < 2; ++sub) {
      const int kb = kc + sub * 16;
      const size_t koff = ((size_t)bh * S_LEN + kb + col) * D_HD + g * 8;
      bf16x8 ak0 = ld8s(Kg + koff,      1.0f);
      bf16x8 ak1 = ld8s(Kg + koff + 32, 1.0f);
      f32x4 acc = {0.f, 0.f, 0.f, 0.f};
      acc = __builtin_amdgcn_mfma_f32_16x16x32_bf16(ak0, bq0, acc, 0, 0, 0);
      acc = __builtin_amdgcn_mfma_f32_16x16x32_bf16(ak1, bq1, acc, 0, 0, 0);
#pragma unroll
      for (int r = 0; r < 4; ++r) {
        bool msk;
        if constexpr (USE_BITS) msk = (mw >> (sub * 16 + g * 4 + r)) & 1;
        else msk = mask_at(mask, mmode, mrow + (size_t)q * S_LEN + kb + g * 4 + r);
        lsum += msk ? 0.f : __expf(acc[r]);
      }
    }
  }
  lsum += __shfl_xor(lsum, 16);          // reduce across g (4 lanes per q)
  lsum += __shfl_xor(lsum, 32);

  // LDS: V^T double buffer (row stride 36 els = 72 B: 8B-aligned b64 reads,
  // 18-dw rows -> read banks spread over all evens; write conflicts ~4-way).
  __shared__ __align__(16) __bf16 vt[2][2][D_HD][36];
  __shared__ float lsh[8][16];
  __shared__ float csum[4][16][66];

  if (lane < 16) lsh[w][col] = lsum;     // publish half-sum (g==0 lanes)

  // stage V chunk 0 (both k-halves) into buf 0
  auto stage = [&](int it_, int buf_) {
    const int kh2 = tid >> 8;            // 0..1
    const int rem = tid & 255;
    const int kk  = rem >> 3;            // 0..31
    const int d0  = (rem & 7) * 8;
    bf16x8 vv = ld8s(
        Vg + ((size_t)bh * S_LEN + kh2 * (S_LEN / 2) + it_ * 32 + kk) * D_HD + d0,
        1.0f);
#pragma unroll
    for (int j = 0; j < 8; j++) vt[buf_][kh2][d0 + j][kk] = vv[j];
  };
  stage(0, 0);
  __syncthreads();                        // lsh + vt[0] ready
  const float inv_l = 1.0f / (lsum + lsh[w ^ 4][col]);

  // ---------------- Pass 2: probs (f32, float4 stores) + PV -----------------
  f32x4 cacc[4];
#pragma unroll
  for (int dt = 0; dt < 4; dt++) cacc[dt] = (f32x4){0.f, 0.f, 0.f, 0.f};

  float* prow = out_p + (size_t)bh * S_LEN * S_LEN + (size_t)q * S_LEN;

  for (int it = 0; it < S_LEN / 64; ++it) {   // 32 iters, ONE barrier each
    const int cur = it & 1;
    if (it < 31) stage(it + 1, cur ^ 1);      // prefetch next V chunk

    const int kc = k0 + it * 32;
    unsigned mw = 0;
    if constexpr (USE_BITS) mw = mbits[mbase + (kc >> 5)];

    float p[8];
#pragma unroll
    for (int sub = 0; sub < 2; ++sub) {
      const int kb = kc + sub * 16;
      const size_t koff = ((size_t)bh * S_LEN + kb + col) * D_HD + g * 8;
      bf16x8 ak0 = ld8s(Kg + koff,      1.0f);
      bf16x8 ak1 = ld8s(Kg + koff + 32, 1.0f);
      f32x4 acc = {0.f, 0.f, 0.f, 0.f};
      acc = __builtin_amdgcn_mfma_f32_16x16x32_bf16(ak0, bq0, acc, 0, 0, 0);
      acc = __builtin_amdgcn_mfma_f32_16x16x32_bf16(ak1, bq1, acc, 0, 0, 0);
#pragma unroll
      for (int r = 0; r < 4; ++r) {
        bool msk;
        if constexpr (USE_BITS) msk = (mw >> (sub * 16 + g * 4 + r)) & 1;
        else msk = mask_at(mask, mmode, mrow + (size_t)q * S_LEN + kb + g * 4 + r);
        p[sub * 4 + r] = msk ? 0.f : __expf(acc[r]) * inv_l;
      }
      float4 st = {p[sub * 4 + 0], p[sub * 4 + 1], p[sub * 4 + 2], p[sub * 4 + 3]};
      *(float4*)(prow + kb + g * 4) = st;       // coalesced 16B/lane
    }
    // P -> bf16 A-frag (k-order sigma(g,e) = (e>>2)*16 + g*4 + (e&3))
    bf16x8 pa;
#pragma unroll
    for (int e = 0; e < 8; e++) pa[e] = (__bf16)p[e];

    // PV: V B-frag with the same sigma: elems 0-3 <- vt[d][g*4+0..3],
    // elems 4-7 <- vt[d][16+g*4+0..3].
#pragma unroll
    for (int dt = 0; dt < 4; dt++) {
      const __bf16* vrow = &vt[cur][kh][dt * 16 + col][0];
      bf16x4 lo = *(const bf16x4*)(vrow + g * 4);
      bf16x4 hi = *(const bf16x4*)(vrow + 16 + g * 4);
      bf16x8 vf = __builtin_shufflevector(lo, hi, 0, 1, 2, 3, 4, 5, 6, 7);
      cacc[dt] = __builtin_amdgcn_mfma_f32_16x16x32_bf16(pa, vf, cacc[dt], 0, 0, 0);
    }
    __syncthreads();                      // vt[cur^1] staged; vt[cur] reads done
  }

  // ---------------- epilogue: merge k-halves, write context -----------------
  // PV C-layout: row=(lane>>4)*4+r = q-slot, col = d within dt*16.
  if (kh == 1) {
#pragma unroll
    for (int dt = 0; dt < 4; dt++)
#pragma unroll
      for (int r = 0; r < 4; r++)
        csum[qw][g * 4 + r][dt * 16 + col] = cacc[dt][r];
  }
  __syncthreads();
  if (kh == 0) {
#pragma unroll
    for (int dt = 0; dt < 4; dt++)
#pragma unroll
      for (int r = 0; r < 4; r++)
        out_ctx[((size_t)bh * S_LEN + qbase + g * 4 + r) * D_HD + dt * 16 + col] =
            cacc[dt][r] + csum[qw][g * 4 + r][dt * 16 + col];
  }
}

extern "C" void kernel_launch(void* const* d_in, const int* in_sizes, int n_in,
                              void* d_out, int out_size, void* d_ws, size_t ws_size,
                              hipStream_t stream) {
  const float* Q = (const float*)d_in[0];
  const float* K = (const float*)d_in[1];
  const float* V = (const float*)d_in[2];
  const void* mask = d_in[3];
  float* out = (float*)d_out;

  const size_t mask_elems = (size_t)B_SZ * S_LEN * S_LEN;   // 8,388,608
  const size_t off_bits = 256;
  const size_t off_q = off_bits + mask_elems / 8;           // +1 MB
  const size_t off_k = off_q + NQ_EL * 2;
  const size_t off_v = off_k + NQ_EL * 2;
  const size_t need  = off_v + NQ_EL * 2;                   // ~19.9 MB
  dim3 grid(S_LEN / 64, B_SZ * NH);                         // 32 x 24 = 768

  if (ws_size >= need) {
    unsigned* bits = (unsigned*)((char*)d_ws + off_bits);
    __bf16* Qb = (__bf16*)((char*)d_ws + off_q);
    __bf16* Kb = (__bf16*)((char*)d_ws + off_k);
    __bf16* Vb = (__bf16*)((char*)d_ws + off_v);
    build_bits_kernel<<<(unsigned)(mask_elems / 256), 256, 0, stream>>>(mask, bits);
    convert_kernel<<<2048, 256, 0, stream>>>(Q, K, V, Qb, Kb, Vb);
    attn_kernel<__bf16, true, true><<<grid, 512, 0, stream>>>(
        Qb, Kb, Vb, mask, bits, out);
  } else if (ws_size >= off_q) {
    unsigned* bits = (unsigned*)((char*)d_ws + off_bits);
    build_bits_kernel<<<(unsigned)(mask_elems / 256), 256, 0, stream>>>(mask, bits);
    attn_kernel<float, true, false><<<grid, 512, 0, stream>>>(
        Q, K, V, mask, bits, out);
  } else {
    attn_kernel<float, false, false><<<grid, 512, 0, stream>>>(
        Q, K, V, mask, nullptr, out);
  }
}